// Round 3
// baseline (197.613 us; speedup 1.0000x reference)
//
#include <hip/hip_runtime.h>

// ContrastiveLoss on MI355X (gfx950) — round 3
// loss = (1/n) sum_i [ P_i*(10+log z_i) - 10*possum_i ]
//   z_i      = sum_{j != i} exp(10*dot_ij - 10)
//   possum_i = sum_{j != i, lab_j==lab_i} dot_ij      (folded into the MFMA pass)
// zsum: 128x128 block tile; B staged global->VGPR->ds_write_b128 (cache-friendly
// path; R2's global_load_lds staging caused 300 MB/dispatch phantom HBM traffic).

#define N 8192
#define D 128
#define JSPLIT 16
#define IBLK 128
#define JTILE 128
#define K2E 14.4269504088896340736f   // 10*log2(e)

typedef __bf16 bf16x8 __attribute__((ext_vector_type(8)));
typedef float f32x4 __attribute__((ext_vector_type(4)));

// ws layout (bytes)
#define EBF_OFF  0          // bf16 E, fragment-major: 8192*256 B = 2 MB
#define CNT_OFF  2097152    // class counts: 100*4, padded to 512
#define Z_OFF    2097664    // z per row: 32 KB
#define S_OFF    2130432    // possum per row: 32 KB
#define ZERO_SZ  (512 + 32768 + 32768)

__device__ __forceinline__ unsigned short f32_to_bf16_rne(float f) {
    unsigned int u = __float_as_uint(f);
    u += 0x7fffu + ((u >> 16) & 1u);
    return (unsigned short)(u >> 16);
}

// Fragment-major layout of E:
//   row r: grp = r>>4, col = r&15 ; element k: c = k>>5, q = (k>>3)&3, jj = k&7
//   byte = grp*4096 + c*1024 + q*256 + col*16 + jj*2
// -> A/B fragment chunk c of 16-row group g: lane reads 16B at g*4096+c*1024+lane*16.

// Kernel 1: normalize rows -> fragment-major bf16 E; class histogram.
__global__ __launch_bounds__(256) void prep_kernel(
        const float* __restrict__ emb, const int* __restrict__ labels,
        unsigned char* __restrict__ ebf, int* __restrict__ cnt) {
    const int wave = threadIdx.x >> 6;
    const int lane = threadIdx.x & 63;
    const int row  = blockIdx.x * 4 + wave;

    const float2 v = *(const float2*)(emb + (size_t)row * D + lane * 2);
    float ss = v.x * v.x + v.y * v.y;
    #pragma unroll
    for (int off = 32; off; off >>= 1) ss += __shfl_xor(ss, off);
    const float inv = 1.0f / fmaxf(sqrtf(ss), 1e-12f);

    const int grp = row >> 4, col = row & 15;
    const int c = lane >> 4, q = (lane >> 2) & 3, j2 = lane & 3;
    unsigned int packed = (unsigned int)f32_to_bf16_rne(v.x * inv) |
                          ((unsigned int)f32_to_bf16_rne(v.y * inv) << 16);
    *(unsigned int*)(ebf + grp * 4096 + c * 1024 + q * 256 + col * 16 + j2 * 4) = packed;

    if (lane == 0) atomicAdd(&cnt[labels[row]], 1);
}

// Kernel 2: fused z + possum. Block: 4 waves x 32 i-rows = 128 i-rows.
// grid (N/IBLK, JSPLIT); each block sweeps 512 j-rows as 4 LDS tiles of 128.
__global__ __launch_bounds__(256, 4) void zsum_kernel(
        const unsigned char* __restrict__ ebf, const int* __restrict__ labels,
        float* __restrict__ z, float* __restrict__ s) {
    __shared__ __align__(16) unsigned char sm[JTILE * 256];   // 32 KB

    const int t    = threadIdx.x;
    const int w    = t >> 6;
    const int lane = t & 63;
    const int q    = lane >> 4;
    const int col  = lane & 15;
    const int i0   = blockIdx.x * IBLK;
    const int jb   = blockIdx.y * (N / JSPLIT);

    // A fragments (2 groups of 16 i-rows) + own labels (4 rows per g per lane)
    bf16x8 a[2][4];
    int labi[2][4];
    #pragma unroll
    for (int g = 0; g < 2; ++g) {
        const unsigned char* ag = ebf + (size_t)(i0 / 16 + w * 2 + g) * 4096 + lane * 16;
        #pragma unroll
        for (int c = 0; c < 4; ++c) a[g][c] = *(const bf16x8*)(ag + c * 1024);
        const int4 li = *(const int4*)(labels + i0 + w * 32 + g * 16 + q * 4);
        labi[g][0] = li.x; labi[g][1] = li.y; labi[g][2] = li.z; labi[g][3] = li.w;
    }

    float zacc[2][4] = {{0.f,0.f,0.f,0.f},{0.f,0.f,0.f,0.f}};
    float pacc[2][4] = {{0.f,0.f,0.f,0.f},{0.f,0.f,0.f,0.f}};

    for (int jt = 0; jt < (N / JSPLIT) / JTILE; ++jt) {
        const int j0 = jb + jt * JTILE;
        if (jt) __syncthreads();
        // stage 32 KB: identity copy, 16B/thread/iter, two batches of 4 (VGPR cap)
        {
            const int4* gsrc = (const int4*)(ebf + (size_t)j0 * 256) + t;
            int4* ldst = (int4*)sm + t;
            int4 b0 = gsrc[0*256], b1 = gsrc[1*256], b2 = gsrc[2*256], b3 = gsrc[3*256];
            ldst[0*256] = b0; ldst[1*256] = b1; ldst[2*256] = b2; ldst[3*256] = b3;
            int4 b4 = gsrc[4*256], b5 = gsrc[5*256], b6 = gsrc[6*256], b7 = gsrc[7*256];
            ldst[4*256] = b4; ldst[5*256] = b5; ldst[6*256] = b6; ldst[7*256] = b7;
        }
        __syncthreads();

        #pragma unroll
        for (int st = 0; st < 8; ++st) {
            bf16x8 b[4];
            #pragma unroll
            for (int c = 0; c < 4; ++c)
                b[c] = *(const bf16x8*)(sm + st * 4096 + c * 1024 + lane * 16);
            const int js   = j0 + st * 16;
            const int labj = labels[js + col];
            #pragma unroll
            for (int g = 0; g < 2; ++g) {
                f32x4 acc = {0.f, 0.f, 0.f, 0.f};
                #pragma unroll
                for (int c = 0; c < 4; ++c)
                    acc = __builtin_amdgcn_mfma_f32_16x16x32_bf16(a[g][c], b[c], acc, 0, 0, 0);
                const int ig = i0 + w * 32 + g * 16;
                if (js == ig) {                       // wave-uniform diagonal tile
                    #pragma unroll
                    for (int r = 0; r < 4; ++r) {
                        const bool self = (col == q * 4 + r);
                        const float e = exp2f(fmaf(acc[r], K2E, -K2E));
                        zacc[g][r] += self ? 0.0f : e;
                        pacc[g][r] += (!self && labj == labi[g][r]) ? acc[r] : 0.0f;
                    }
                } else {
                    #pragma unroll
                    for (int r = 0; r < 4; ++r) {
                        zacc[g][r] += exp2f(fmaf(acc[r], K2E, -K2E));
                        pacc[g][r] += (labj == labi[g][r]) ? acc[r] : 0.0f;
                    }
                }
            }
        }
    }

    // per-row reduce across the 16 cols of each quad, atomic merge of partials
    #pragma unroll
    for (int g = 0; g < 2; ++g)
        #pragma unroll
        for (int r = 0; r < 4; ++r) {
            float zv = zacc[g][r], pv = pacc[g][r];
            zv += __shfl_xor(zv, 1); pv += __shfl_xor(pv, 1);
            zv += __shfl_xor(zv, 2); pv += __shfl_xor(pv, 2);
            zv += __shfl_xor(zv, 4); pv += __shfl_xor(pv, 4);
            zv += __shfl_xor(zv, 8); pv += __shfl_xor(pv, 8);
            if (col == 0) {
                const int row = i0 + w * 32 + g * 16 + q * 4 + r;
                atomicAdd(&z[row], zv);
                atomicAdd(&s[row], pv);
            }
        }
}

// Kernel 3: single-block epilogue (no out-memset needed).
__global__ __launch_bounds__(1024) void final_kernel(
        const int* __restrict__ labels, const int* __restrict__ cnt,
        const float* __restrict__ z, const float* __restrict__ s,
        float* __restrict__ out) {
    __shared__ float part[16];
    const int tid = threadIdx.x;
    float acc = 0.0f;
    #pragma unroll
    for (int k = 0; k < N / 1024; ++k) {
        const int row = k * 1024 + tid;
        const int P = cnt[labels[row]] - 1;
        if (P > 0)
            acc += (float)P * (10.0f + logf(z[row])) - 10.0f * s[row];
    }
    #pragma unroll
    for (int off = 32; off; off >>= 1) acc += __shfl_xor(acc, off);
    if ((tid & 63) == 0) part[tid >> 6] = acc;
    __syncthreads();
    if (tid == 0) {
        float tot = 0.0f;
        #pragma unroll
        for (int w = 0; w < 16; ++w) tot += part[w];
        out[0] = tot * (1.0f / (float)N);
    }
}

extern "C" void kernel_launch(void* const* d_in, const int* in_sizes, int n_in,
                              void* d_out, int out_size, void* d_ws, size_t ws_size,
                              hipStream_t stream) {
    const float* emb  = (const float*)d_in[0];
    const int* labels = (const int*)d_in[1];
    float* out        = (float*)d_out;
    char* ws          = (char*)d_ws;

    unsigned char* ebf = (unsigned char*)(ws + EBF_OFF);
    int*   cnt         = (int*)(ws + CNT_OFF);
    float* z           = (float*)(ws + Z_OFF);
    float* s           = (float*)(ws + S_OFF);

    hipMemsetAsync(ws + CNT_OFF, 0, ZERO_SZ, stream);

    prep_kernel<<<N / 4, 256, 0, stream>>>(emb, labels, ebf, cnt);
    zsum_kernel<<<dim3(N / IBLK, JSPLIT), 256, 0, stream>>>(ebf, labels, z, s);
    final_kernel<<<1, 1024, 0, stream>>>(labels, cnt, z, s, out);
}

// Round 4
// 131.960 us; speedup vs baseline: 1.4975x; 1.4975x over previous
//
#include <hip/hip_runtime.h>

// ContrastiveLoss on MI355X (gfx950) — round 4
// loss = (1/n) sum_i [ P_i*(10+log z_i) - 10*possum_i ]
//   z_i      = sum_{j != i} exp(10*dot_ij - 10)
//   possum_i = sum_{j != i, lab_j==lab_i} dot_ij
// R4: NO LDS, NO barriers in zsum. Fragment-major E makes B-fragments directly
// loadable as coalesced 1KB global_load_dwordx4; waves are fully independent
// (R1-R3 all stalled on barrier-synchronized staging latency). Each wave holds
// 64 i-rows of A in registers -> 4 MFMAs amortize every B-chunk load.

#define N 8192
#define D 128
#define JSPLIT 32         // grid.y; j-window = N/JSPLIT = 256 rows
#define IBLK 256          // i-rows per block (4 waves x 64)
#define K2E 14.4269504088896340736f   // 10*log2(e)

typedef __bf16 bf16x8 __attribute__((ext_vector_type(8)));
typedef float f32x4 __attribute__((ext_vector_type(4)));

// ws layout (bytes)
#define EBF_OFF  0          // bf16 E, fragment-major: 8192*256 B = 2 MB
#define CNT_OFF  2097152    // class counts: 100*4, padded to 512
#define Z_OFF    2097664    // z per row: 32 KB
#define S_OFF    2130432    // possum per row: 32 KB
#define ZERO_SZ  (512 + 32768 + 32768)

__device__ __forceinline__ unsigned short f32_to_bf16_rne(float f) {
    unsigned int u = __float_as_uint(f);
    u += 0x7fffu + ((u >> 16) & 1u);
    return (unsigned short)(u >> 16);
}

// Fragment-major layout of E:
//   row r: grp = r>>4, col = r&15 ; element k: c = k>>5, q = (k>>3)&3, jj = k&7
//   byte = grp*4096 + c*1024 + q*256 + col*16 + jj*2
// A/B fragment chunk c of 16-row group g: lane reads 16B at g*4096 + c*1024 + lane*16
// -> one fully-coalesced 1KB global_load_dwordx4 per chunk.

// Kernel 1: normalize rows -> fragment-major bf16 E; class histogram.
__global__ __launch_bounds__(256) void prep_kernel(
        const float* __restrict__ emb, const int* __restrict__ labels,
        unsigned char* __restrict__ ebf, int* __restrict__ cnt) {
    const int wave = threadIdx.x >> 6;
    const int lane = threadIdx.x & 63;
    const int row  = blockIdx.x * 4 + wave;

    const float2 v = *(const float2*)(emb + (size_t)row * D + lane * 2);
    float ss = v.x * v.x + v.y * v.y;
    #pragma unroll
    for (int off = 32; off; off >>= 1) ss += __shfl_xor(ss, off);
    const float inv = 1.0f / fmaxf(sqrtf(ss), 1e-12f);

    const int grp = row >> 4, col = row & 15;
    const int c = lane >> 4, q = (lane >> 2) & 3, j2 = lane & 3;
    unsigned int packed = (unsigned int)f32_to_bf16_rne(v.x * inv) |
                          ((unsigned int)f32_to_bf16_rne(v.y * inv) << 16);
    *(unsigned int*)(ebf + grp * 4096 + c * 1024 + q * 256 + col * 16 + j2 * 4) = packed;

    if (lane == 0) atomicAdd(&cnt[labels[row]], 1);
}

// Kernel 2: fused z + possum. Block = 4 waves; wave owns 64 i-rows (4 groups).
// grid (N/IBLK, JSPLIT). No LDS, no barriers — B read directly from global.
__global__ __launch_bounds__(256) void zsum_kernel(
        const unsigned char* __restrict__ ebf, const int* __restrict__ labels,
        float* __restrict__ z, float* __restrict__ s) {
    const int t    = threadIdx.x;
    const int w    = t >> 6;
    const int lane = t & 63;
    const int q    = lane >> 4;
    const int col  = lane & 15;
    const int iw   = blockIdx.x * IBLK + w * 64;    // this wave's first i-row
    const int jb   = blockIdx.y * (N / JSPLIT);

    // A fragments: 4 groups of 16 i-rows, 4 K-chunks each (coalesced 1KB loads)
    bf16x8 a[4][4];
    int labi[4][4];
    #pragma unroll
    for (int g = 0; g < 4; ++g) {
        const unsigned char* ag = ebf + (size_t)(iw / 16 + g) * 4096 + lane * 16;
        #pragma unroll
        for (int c = 0; c < 4; ++c) a[g][c] = *(const bf16x8*)(ag + c * 1024);
        const int4 li = *(const int4*)(labels + iw + g * 16 + q * 4);
        labi[g][0] = li.x; labi[g][1] = li.y; labi[g][2] = li.z; labi[g][3] = li.w;
    }

    float zacc[4][4] = {{0.f,0.f,0.f,0.f},{0.f,0.f,0.f,0.f},
                        {0.f,0.f,0.f,0.f},{0.f,0.f,0.f,0.f}};
    float pacc[4][4] = {{0.f,0.f,0.f,0.f},{0.f,0.f,0.f,0.f},
                        {0.f,0.f,0.f,0.f},{0.f,0.f,0.f,0.f}};

    #pragma unroll 4
    for (int jt = 0; jt < (N / JSPLIT) / 16; ++jt) {
        const int js = jb + jt * 16;
        const unsigned char* bg = ebf + (size_t)(js / 16) * 4096 + lane * 16;
        bf16x8 b[4];
        #pragma unroll
        for (int c = 0; c < 4; ++c) b[c] = *(const bf16x8*)(bg + c * 1024);
        const int labj = labels[js + col];

        #pragma unroll
        for (int g = 0; g < 4; ++g) {
            f32x4 acc = {0.f, 0.f, 0.f, 0.f};
            #pragma unroll
            for (int c = 0; c < 4; ++c)
                acc = __builtin_amdgcn_mfma_f32_16x16x32_bf16(a[g][c], b[c], acc, 0, 0, 0);
            if (js == iw + g * 16) {                  // wave-uniform diagonal tile
                #pragma unroll
                for (int r = 0; r < 4; ++r) {
                    const bool self = (col == q * 4 + r);
                    zacc[g][r] += self ? 0.0f : exp2f(fmaf(acc[r], K2E, -K2E));
                    pacc[g][r] += (!self && labj == labi[g][r]) ? acc[r] : 0.0f;
                }
            } else {
                #pragma unroll
                for (int r = 0; r < 4; ++r) {
                    zacc[g][r] += exp2f(fmaf(acc[r], K2E, -K2E));
                    pacc[g][r] += (labj == labi[g][r]) ? acc[r] : 0.0f;
                }
            }
        }
    }

    // per-row reduce across the 16 cols of each quad, atomic merge of partials
    #pragma unroll
    for (int g = 0; g < 4; ++g)
        #pragma unroll
        for (int r = 0; r < 4; ++r) {
            float zv = zacc[g][r], pv = pacc[g][r];
            zv += __shfl_xor(zv, 1); pv += __shfl_xor(pv, 1);
            zv += __shfl_xor(zv, 2); pv += __shfl_xor(pv, 2);
            zv += __shfl_xor(zv, 4); pv += __shfl_xor(pv, 4);
            zv += __shfl_xor(zv, 8); pv += __shfl_xor(pv, 8);
            if (col == 0) {
                const int row = iw + g * 16 + q * 4 + r;
                atomicAdd(&z[row], zv);
                atomicAdd(&s[row], pv);
            }
        }
}

// Kernel 3: single-block epilogue.
__global__ __launch_bounds__(1024) void final_kernel(
        const int* __restrict__ labels, const int* __restrict__ cnt,
        const float* __restrict__ z, const float* __restrict__ s,
        float* __restrict__ out) {
    __shared__ float part[16];
    const int tid = threadIdx.x;
    float acc = 0.0f;
    #pragma unroll
    for (int k = 0; k < N / 1024; ++k) {
        const int row = k * 1024 + tid;
        const int P = cnt[labels[row]] - 1;
        if (P > 0)
            acc += (float)P * (10.0f + logf(z[row])) - 10.0f * s[row];
    }
    #pragma unroll
    for (int off = 32; off; off >>= 1) acc += __shfl_xor(acc, off);
    if ((tid & 63) == 0) part[tid >> 6] = acc;
    __syncthreads();
    if (tid == 0) {
        float tot = 0.0f;
        #pragma unroll
        for (int w = 0; w < 16; ++w) tot += part[w];
        out[0] = tot * (1.0f / (float)N);
    }
}

extern "C" void kernel_launch(void* const* d_in, const int* in_sizes, int n_in,
                              void* d_out, int out_size, void* d_ws, size_t ws_size,
                              hipStream_t stream) {
    const float* emb  = (const float*)d_in[0];
    const int* labels = (const int*)d_in[1];
    float* out        = (float*)d_out;
    char* ws          = (char*)d_ws;

    unsigned char* ebf = (unsigned char*)(ws + EBF_OFF);
    int*   cnt         = (int*)(ws + CNT_OFF);
    float* z           = (float*)(ws + Z_OFF);
    float* s           = (float*)(ws + S_OFF);

    hipMemsetAsync(ws + CNT_OFF, 0, ZERO_SZ, stream);

    prep_kernel<<<N / 4, 256, 0, stream>>>(emb, labels, ebf, cnt);
    zsum_kernel<<<dim3(N / IBLK, JSPLIT), 256, 0, stream>>>(ebf, labels, z, s);
    final_kernel<<<1, 1024, 0, stream>>>(labels, cnt, z, s, out);
}